// Round 17
// baseline (152.862 us; speedup 1.0000x reference)
//
#include <hip/hip_runtime.h>

#define SDIM 4096
#define HDIM 256
#define WIN 128
#define NROW 16384  // B*S
#define QSCALE 0.0625f  // 1/sqrt(256)

typedef __attribute__((ext_vector_type(8))) short bf16x8;
typedef __attribute__((ext_vector_type(4))) float f32x4;

static __device__ __forceinline__ unsigned short f2bf(float f) {
  unsigned int u = __float_as_uint(f);
  return (unsigned short)((u + 0x7fffu + ((u >> 16) & 1u)) >> 16);
}

#define MFMA16(a, b, c) __builtin_amdgcn_mfma_f32_16x16x32_bf16((a), (b), (c), 0, 0, 0)

// Frag-packed layout (per 16-row tile, per kk): pack[tile][kk][lane][j] =
//   M[16*tile + (lane&15)][32*kk + 8*(lane>>4) + j]  -> wave load = base+lane*8.
// V PV-packed: Vp[tile][dt][gg][l15][j] = V[16*tile + 8*gg + j][16*dt + l15].

// ---------- Kernel 0: W -> frag-packed bf16 W^T (frozen) ----------
__global__ __launch_bounds__(256) void wconv(const float* __restrict__ Wq,
                                             const float* __restrict__ Wk,
                                             const float* __restrict__ Wv,
                                             unsigned short* __restrict__ Wp) {
  const int m = blockIdx.y, nt = blockIdx.x;
  const float* __restrict__ W = (m == 0) ? Wq : (m == 1) ? Wk : Wv;
  const int tid = threadIdx.x, lane = tid & 63, w = tid >> 6;
  const int l15 = lane & 15, g = lane >> 4;
#pragma unroll
  for (int half = 0; half < 2; ++half) {
    int kk = w * 2 + half;
    bf16x8 v;
#pragma unroll
    for (int j = 0; j < 8; ++j)
      v[j] = (short)f2bf(W[(size_t)(32 * kk + 8 * g + j) * HDIM + 16 * nt + l15]);
    *(bf16x8*)(Wp + ((size_t)(m * 16 + nt) * 8 + kk) * 512 + (size_t)lane * 8) = v;
  }
}

// ---------- Kernel 1: QKV (R13 structure), x3 REP for observability --------
// Reps re-execute the whole body; all writes are value-identical -> output
// unchanged. Dispatch runs ~3x its true time -> visible in rocprof top-5.
__global__ __launch_bounds__(256) void qkv_mfma(
    const float* __restrict__ x, const unsigned short* __restrict__ Wp,
    const float* __restrict__ bq, const float* __restrict__ bk,
    const float* __restrict__ bv, unsigned short* __restrict__ Qp,
    unsigned short* __restrict__ Kp, unsigned short* __restrict__ Vp) {
  __shared__ unsigned short st[32][264];
  const int tid = threadIdx.x;
  const int lane = tid & 63, w = tid >> 6;
  const int l15 = lane & 15, g = lane >> 4;
  const size_t rb = (size_t)blockIdx.x * 32;
#pragma unroll 1
  for (int rep = 0; rep < 3; ++rep) {
    asm volatile("" ::: "memory");  // no cross-rep CSE
#pragma unroll
    for (int it = 0; it < 8; ++it) {
      int u = it * 256 + tid;
      int r = u >> 6, c4 = (u & 63) << 2;
      float4 f = *(const float4*)(x + (rb + r) * HDIM + c4);
      st[r][c4 + 0] = f2bf(f.x);
      st[r][c4 + 1] = f2bf(f.y);
      st[r][c4 + 2] = f2bf(f.z);
      st[r][c4 + 3] = f2bf(f.w);
    }
    __syncthreads();
    bf16x8 a[2][8];
#pragma unroll
    for (int rtl = 0; rtl < 2; ++rtl)
#pragma unroll
      for (int kk = 0; kk < 8; ++kk)
        a[rtl][kk] = *(const bf16x8*)&st[16 * rtl + l15][32 * kk + 8 * g];
    __syncthreads();
    const int tg0 = blockIdx.x * 2;
    for (int m = 0; m < 3; ++m) {
      const unsigned short* Wm = Wp + (size_t)m * 65536;
      const float* bias = (m == 0) ? bq : (m == 1) ? bk : bv;
#pragma unroll
      for (int ntl = 0; ntl < 4; ++ntl) {
        const int nt = 4 * w + ntl;
        const unsigned short* wp_ = Wm + (size_t)nt * 4096 + (size_t)lane * 8;
        bf16x8 wf[8];
#pragma unroll
        for (int kk = 0; kk < 8; ++kk) wf[kk] = *(const bf16x8*)(wp_ + kk * 512);
        f32x4 a0 = {0.f, 0.f, 0.f, 0.f}, a1 = {0.f, 0.f, 0.f, 0.f};
#pragma unroll
        for (int kk = 0; kk < 8; ++kk) {
          a0 = MFMA16(a[0][kk], wf[kk], a0);
          a1 = MFMA16(a[1][kk], wf[kk], a1);
        }
        float bn = bias[nt * 16 + l15];
#pragma unroll
        for (int r = 0; r < 4; ++r) {
          st[4 * g + r][nt * 16 + l15] = f2bf(a0[r] + bn);
          st[16 + 4 * g + r][nt * 16 + l15] = f2bf(a1[r] + bn);
        }
      }
      __syncthreads();
      if (m < 2) {
        unsigned short* O = (m == 0 ? Qp : Kp);
#pragma unroll
        for (int it = 0; it < 4; ++it) {
          int u = it * 256 + tid;
          int ln = u & 63, kk = (u >> 6) & 7, tgl = u >> 9;
          int lg = ln >> 4, lc = ln & 15;
          bf16x8 vv = *(const bf16x8*)&st[16 * tgl + lc][32 * kk + 8 * lg];
          *(bf16x8*)(O + ((size_t)(tg0 + tgl) * 8 + kk) * 512 + (size_t)ln * 8) = vv;
        }
      } else {
#pragma unroll
        for (int it = 0; it < 4; ++it) {
          int u = it * 256 + tid;
          int lc = u & 15, gg = (u >> 4) & 1, dt = (u >> 5) & 15, tgl = u >> 9;
          bf16x8 vv;
#pragma unroll
          for (int j = 0; j < 8; ++j)
            vv[j] = (short)st[16 * tgl + 8 * gg + j][16 * dt + lc];
          *(bf16x8*)(Vp + (size_t)(tg0 + tgl) * 4096 +
                     (size_t)(dt * 32 + gg * 16 + lc) * 8) = vv;
        }
      }
      __syncthreads();
    }
  }
}

// ---------- Kernel 2: attention (R13 structure), x3 REP for observability --
// acc/lacc scale by 3; epilogue normalizes acc/l -> factor cancels exactly.
__global__ __launch_bounds__(256) void attn_mfma(
    const unsigned short* __restrict__ Qp, const unsigned short* __restrict__ Kp,
    const unsigned short* __restrict__ Vp, float* __restrict__ partial) {
  __shared__ unsigned short plds[4][2][16][40];
  __shared__ float lsh[4][16];
  __shared__ float fbuf[4][256];
  const int tid = threadIdx.x;
  const int lane = tid & 63, w = tid >> 6;
  const int bid = blockIdx.x;
  const int blk = (bid & 7) * 128 + (bid >> 3);  // bijective XCD swizzle
  const int b = blk >> 8;
  const int qt = blk & 255;
  const int s0 = qt << 4;
  const int l15 = lane & 15, g = lane >> 4;
  bf16x8 qf[8];
  const unsigned short* qp_ = Qp + ((size_t)b * 256 + qt) * 4096 + (size_t)lane * 8;
#pragma unroll
  for (int kk = 0; kk < 8; ++kk) qf[kk] = *(const bf16x8*)(qp_ + kk * 512);
  const unsigned short* Kb = Kp + (size_t)b * 1048576;
  const unsigned short* Vb = Vp + (size_t)b * 1048576;
  f32x4 acc[16];
  const f32x4 zero = {0.f, 0.f, 0.f, 0.f};
#pragma unroll
  for (int i = 0; i < 16; ++i) acc[i] = zero;
  float lacc[4] = {0.f, 0.f, 0.f, 0.f};
#pragma unroll 1
  for (int rep = 0; rep < 3; ++rep) {
    asm volatile("" ::: "memory");  // no cross-rep CSE
    // ---- fused dual chunk: chunks 2w and 2w+1 ----
    const int t0A = s0 - WIN + 64 * w;
    const int tgA = qt - 8 + 4 * w;
    const int tg0 = min(max(tgA + 0, 0), 255);
    const int tg1 = min(max(tgA + 1, 0), 255);
    const int tg2 = min(max(tgA + 2, 0), 255);
    const int tg3 = min(max(tgA + 3, 0), 255);
    const unsigned short* k0p = Kb + (size_t)tg0 * 4096 + (size_t)lane * 8;
    const unsigned short* k1p = Kb + (size_t)tg1 * 4096 + (size_t)lane * 8;
    const unsigned short* k2p = Kb + (size_t)tg2 * 4096 + (size_t)lane * 8;
    const unsigned short* k3p = Kb + (size_t)tg3 * 4096 + (size_t)lane * 8;
    f32x4 sc0 = zero, sc1 = zero, sc2 = zero, sc3 = zero;
#pragma unroll
    for (int kk = 0; kk < 8; ++kk) {
      sc0 = MFMA16(qf[kk], *(const bf16x8*)(k0p + kk * 512), sc0);
      sc1 = MFMA16(qf[kk], *(const bf16x8*)(k1p + kk * 512), sc1);
      sc2 = MFMA16(qf[kk], *(const bf16x8*)(k2p + kk * 512), sc2);
      sc3 = MFMA16(qf[kk], *(const bf16x8*)(k3p + kk * 512), sc3);
    }
    float p[4][4];
#pragma unroll
    for (int r = 0; r < 4; ++r) {
      const int s = s0 + 4 * g + r;
      const f32x4 sv[4] = {sc0, sc1, sc2, sc3};
#pragma unroll
      for (int ti = 0; ti < 4; ++ti) {
        int t = t0A + 16 * ti + l15;
        bool ok = (t >= 0) && (t < SDIM) && (t - s <= WIN) && (t - s >= -WIN);
        p[ti][r] = ok ? __expf(sv[ti][r] * QSCALE) : 0.f;
      }
    }
#pragma unroll
    for (int r = 0; r < 4; ++r) {
      float v = p[0][r] + p[1][r] + p[2][r] + p[3][r];
      v += __shfl_xor(v, 1);
      v += __shfl_xor(v, 2);
      v += __shfl_xor(v, 4);
      v += __shfl_xor(v, 8);
      lacc[r] += v;
    }
#pragma unroll
    for (int r = 0; r < 4; ++r) {
      plds[w][0][4 * g + r][l15] = f2bf(p[0][r]);
      plds[w][0][4 * g + r][16 + l15] = f2bf(p[1][r]);
      plds[w][1][4 * g + r][l15] = f2bf(p[2][r]);
      plds[w][1][4 * g + r][16 + l15] = f2bf(p[3][r]);
    }
    bf16x8 paA = *(const bf16x8*)&plds[w][0][l15][8 * g];
    bf16x8 paB = *(const bf16x8*)&plds[w][1][l15][8 * g];
    const int tgvA = min(max(tgA + (g >> 1), 0), 255);
    const int tgvB = min(max(tgA + 2 + (g >> 1), 0), 255);
    const unsigned short* vpA =
        Vb + (size_t)tgvA * 4096 + (size_t)(g & 1) * 128 + (size_t)l15 * 8;
    const unsigned short* vpB =
        Vb + (size_t)tgvB * 4096 + (size_t)(g & 1) * 128 + (size_t)l15 * 8;
#pragma unroll
    for (int dt = 0; dt < 16; ++dt) {
      acc[dt] = MFMA16(paA, *(const bf16x8*)(vpA + dt * 256), acc[dt]);
      acc[dt] = MFMA16(paB, *(const bf16x8*)(vpB + dt * 256), acc[dt]);
    }
    // ---- wave 3 tail: half-chunk c8 ----
    if (w == 3) {
      const int t0C = s0 + WIN;
      const int tgC = min(qt + 8, 255);
      const unsigned short* kcp = Kb + (size_t)tgC * 4096 + (size_t)lane * 8;
      f32x4 scC = zero;
#pragma unroll
      for (int kk = 0; kk < 8; ++kk)
        scC = MFMA16(qf[kk], *(const bf16x8*)(kcp + kk * 512), scC);
      float pC[4];
#pragma unroll
      for (int r = 0; r < 4; ++r) {
        int s = s0 + 4 * g + r;
        int t = t0C + l15;
        bool ok = (t < SDIM) && (t - s <= WIN);
        pC[r] = ok ? __expf(scC[r] * QSCALE) : 0.f;
        float v = pC[r];
        v += __shfl_xor(v, 1);
        v += __shfl_xor(v, 2);
        v += __shfl_xor(v, 4);
        v += __shfl_xor(v, 8);
        lacc[r] += v;
      }
#pragma unroll
      for (int r = 0; r < 4; ++r) {
        plds[w][0][4 * g + r][l15] = f2bf(pC[r]);
        plds[w][0][4 * g + r][16 + l15] = 0;
      }
      bf16x8 paC = *(const bf16x8*)&plds[w][0][l15][8 * g];
      const int tgvC = min(max(tgC + (g >> 1), 0), 255);
      const unsigned short* vpC =
          Vb + (size_t)tgvC * 4096 + (size_t)(g & 1) * 128 + (size_t)l15 * 8;
#pragma unroll
      for (int dt = 0; dt < 16; ++dt)
        acc[dt] = MFMA16(paC, *(const bf16x8*)(vpC + dt * 256), acc[dt]);
    }
  }
  // ---- epilogue: 2 barriers; li recomputed per-wave from lsh ----
  if (l15 == 0) {
#pragma unroll
    for (int r = 0; r < 4; ++r) lsh[w][4 * g + r] = lacc[r];
  }
  __syncthreads();
  float li[4];
#pragma unroll
  for (int r = 0; r < 4; ++r)
    li[r] = 1.0f / (lsh[0][4 * g + r] + lsh[1][4 * g + r] + lsh[2][4 * g + r] +
                    lsh[3][4 * g + r]);
#pragma unroll
  for (int dt = 0; dt < 16; ++dt) {
    float s = acc[dt][0] * li[0] + acc[dt][1] * li[1] + acc[dt][2] * li[2] +
              acc[dt][3] * li[3];
    s += __shfl_xor(s, 16);
    s += __shfl_xor(s, 32);
    if (lane < 16) fbuf[w][dt * 16 + lane] = s;
  }
  __syncthreads();
  partial[(size_t)blk * HDIM + tid] =
      fbuf[0][tid] + fbuf[1][tid] + fbuf[2][tid] + fbuf[3][tid];
}

// ---------- Kernel 3: deterministic mean over S (frozen) ----------
__global__ __launch_bounds__(256) void reduce_partials(
    const float* __restrict__ partial, float* __restrict__ out) {
  __shared__ float red[16][17];
  const int cx = blockIdx.x, b = blockIdx.y;
  const int lc = threadIdx.x & 15, rg = threadIdx.x >> 4;
  float s = 0.f;
#pragma unroll
  for (int i = 0; i < 16; ++i)
    s += partial[((size_t)b * 256 + rg * 16 + i) * HDIM + cx * 16 + lc];
  red[rg][lc] = s;
  __syncthreads();
  if (rg == 0) {
    float t = 0.f;
#pragma unroll
    for (int r = 0; r < 16; ++r) t += red[r][lc];
    out[(size_t)b * HDIM + cx * 16 + lc] = t * (1.0f / (float)SDIM);
  }
}

extern "C" void kernel_launch(void* const* d_in, const int* in_sizes, int n_in,
                              void* d_out, int out_size, void* d_ws, size_t ws_size,
                              hipStream_t stream) {
  const float* x  = (const float*)d_in[0];
  const float* Wq = (const float*)d_in[1];
  const float* bq = (const float*)d_in[2];
  const float* Wk = (const float*)d_in[3];
  const float* bk = (const float*)d_in[4];
  const float* Wv = (const float*)d_in[5];
  const float* bv = (const float*)d_in[6];
  float* out = (float*)d_out;

  unsigned short* Wp = (unsigned short*)d_ws;           // 384 KB
  unsigned short* Qp = Wp + 3 * 65536;                  // 8.4 MB
  unsigned short* Kp = Qp + (size_t)NROW * HDIM;        // 8.4 MB
  unsigned short* Vp = Kp + (size_t)NROW * HDIM;        // 8.4 MB
  float* partial = (float*)(Vp + (size_t)NROW * HDIM);  // 1 MB

  dim3 wg(16, 3);
  wconv<<<wg, 256, 0, stream>>>(Wq, Wk, Wv, Wp);
  qkv_mfma<<<512, 256, 0, stream>>>(x, Wp, bq, bk, bv, Qp, Kp, Vp);
  attn_mfma<<<1024, 256, 0, stream>>>(Qp, Kp, Vp, partial);
  dim3 rg(16, 4);
  reduce_partials<<<rg, 256, 0, stream>>>(partial, out);
}

// Round 18
// 138.774 us; speedup vs baseline: 1.1015x; 1.1015x over previous
//
#include <hip/hip_runtime.h>

#define SDIM 4096
#define HDIM 256
#define WIN 128
#define NROW 16384  // B*S
#define QSCALE 0.0625f  // 1/sqrt(256)

typedef __attribute__((ext_vector_type(8))) short bf16x8;
typedef __attribute__((ext_vector_type(4))) float f32x4;

static __device__ __forceinline__ unsigned short f2bf(float f) {
  unsigned int u = __float_as_uint(f);
  return (unsigned short)((u + 0x7fffu + ((u >> 16) & 1u)) >> 16);
}

#define MFMA16(a, b, c) __builtin_amdgcn_mfma_f32_16x16x32_bf16((a), (b), (c), 0, 0, 0)

// Frag-packed layout (per 16-row tile, per kk): pack[tile][kk][lane][j] =
//   M[16*tile + (lane&15)][32*kk + 8*(lane>>4) + j]  -> wave load = base+lane*8.
// V PV-packed: Vp[tile][dt][gg][l15][j] = V[16*tile + 8*gg + j][16*dt + l15].

// ---------- Kernel 0: W -> frag-packed bf16 W^T (frozen) ----------
__global__ __launch_bounds__(256) void wconv(const float* __restrict__ Wq,
                                             const float* __restrict__ Wk,
                                             const float* __restrict__ Wv,
                                             unsigned short* __restrict__ Wp) {
  const int m = blockIdx.y, nt = blockIdx.x;
  const float* __restrict__ W = (m == 0) ? Wq : (m == 1) ? Wk : Wv;
  const int tid = threadIdx.x, lane = tid & 63, w = tid >> 6;
  const int l15 = lane & 15, g = lane >> 4;
#pragma unroll
  for (int half = 0; half < 2; ++half) {
    int kk = w * 2 + half;
    bf16x8 v;
#pragma unroll
    for (int j = 0; j < 8; ++j)
      v[j] = (short)f2bf(W[(size_t)(32 * kk + 8 * g + j) * HDIM + 16 * nt + l15]);
    *(bf16x8*)(Wp + ((size_t)(m * 16 + nt) * 8 + kk) * 512 + (size_t)lane * 8) = v;
  }
}

// ---------- Kernel 1: QKV (frozen R13 version) ----------
__global__ __launch_bounds__(256) void qkv_mfma(
    const float* __restrict__ x, const unsigned short* __restrict__ Wp,
    const float* __restrict__ bq, const float* __restrict__ bk,
    const float* __restrict__ bv, unsigned short* __restrict__ Qp,
    unsigned short* __restrict__ Kp, unsigned short* __restrict__ Vp) {
  __shared__ unsigned short st[32][264];
  const int tid = threadIdx.x;
  const int lane = tid & 63, w = tid >> 6;
  const int l15 = lane & 15, g = lane >> 4;
  const size_t rb = (size_t)blockIdx.x * 32;
#pragma unroll
  for (int it = 0; it < 8; ++it) {
    int u = it * 256 + tid;
    int r = u >> 6, c4 = (u & 63) << 2;
    float4 f = *(const float4*)(x + (rb + r) * HDIM + c4);
    st[r][c4 + 0] = f2bf(f.x);
    st[r][c4 + 1] = f2bf(f.y);
    st[r][c4 + 2] = f2bf(f.z);
    st[r][c4 + 3] = f2bf(f.w);
  }
  __syncthreads();
  bf16x8 a[2][8];
#pragma unroll
  for (int rtl = 0; rtl < 2; ++rtl)
#pragma unroll
    for (int kk = 0; kk < 8; ++kk)
      a[rtl][kk] = *(const bf16x8*)&st[16 * rtl + l15][32 * kk + 8 * g];
  __syncthreads();
  const int tg0 = blockIdx.x * 2;
  for (int m = 0; m < 3; ++m) {
    const unsigned short* Wm = Wp + (size_t)m * 65536;
    const float* bias = (m == 0) ? bq : (m == 1) ? bk : bv;
#pragma unroll
    for (int ntl = 0; ntl < 4; ++ntl) {
      const int nt = 4 * w + ntl;
      const unsigned short* wp_ = Wm + (size_t)nt * 4096 + (size_t)lane * 8;
      bf16x8 wf[8];
#pragma unroll
      for (int kk = 0; kk < 8; ++kk) wf[kk] = *(const bf16x8*)(wp_ + kk * 512);
      f32x4 a0 = {0.f, 0.f, 0.f, 0.f}, a1 = {0.f, 0.f, 0.f, 0.f};
#pragma unroll
      for (int kk = 0; kk < 8; ++kk) {
        a0 = MFMA16(a[0][kk], wf[kk], a0);
        a1 = MFMA16(a[1][kk], wf[kk], a1);
      }
      float bn = bias[nt * 16 + l15];
#pragma unroll
      for (int r = 0; r < 4; ++r) {
        st[4 * g + r][nt * 16 + l15] = f2bf(a0[r] + bn);
        st[16 + 4 * g + r][nt * 16 + l15] = f2bf(a1[r] + bn);
      }
    }
    __syncthreads();
    if (m < 2) {
      unsigned short* O = (m == 0 ? Qp : Kp);
#pragma unroll
      for (int it = 0; it < 4; ++it) {
        int u = it * 256 + tid;
        int ln = u & 63, kk = (u >> 6) & 7, tgl = u >> 9;
        int lg = ln >> 4, lc = ln & 15;
        bf16x8 vv = *(const bf16x8*)&st[16 * tgl + lc][32 * kk + 8 * lg];
        *(bf16x8*)(O + ((size_t)(tg0 + tgl) * 8 + kk) * 512 + (size_t)ln * 8) = vv;
      }
    } else {
#pragma unroll
      for (int it = 0; it < 4; ++it) {
        int u = it * 256 + tid;
        int lc = u & 15, gg = (u >> 4) & 1, dt = (u >> 5) & 15, tgl = u >> 9;
        bf16x8 vv;
#pragma unroll
        for (int j = 0; j < 8; ++j)
          vv[j] = (short)st[16 * tgl + 8 * gg + j][16 * dt + lc];
        *(bf16x8*)(Vp + (size_t)(tg0 + tgl) * 4096 +
                   (size_t)(dt * 32 + gg * 16 + lc) * 8) = vv;
      }
    }
    __syncthreads();
  }
}

// ---------- Kernel 2: attention (R13 core) + ticket-based tail reduce ------
// All 1024 blocks co-resident (4/CU). After partial write: fence + ticket.
// Last 64 arrivals spin until all partials visible, then each runs one
// deterministic reduce task (value independent of arrival order).
__global__ __launch_bounds__(256) void attn_mfma(
    const unsigned short* __restrict__ Qp, const unsigned short* __restrict__ Kp,
    const unsigned short* __restrict__ Vp, float* __restrict__ partial,
    float* __restrict__ out, unsigned* __restrict__ cnt) {
  __shared__ unsigned short plds[4][2][16][40];
  __shared__ float lsh[4][16];
  __shared__ float fbuf[4][256];
  __shared__ unsigned ticket;
  const int tid = threadIdx.x;
  const int lane = tid & 63, w = tid >> 6;
  const int bid = blockIdx.x;
  const int blk = (bid & 7) * 128 + (bid >> 3);  // bijective XCD swizzle
  const int b = blk >> 8;
  const int qt = blk & 255;
  const int s0 = qt << 4;
  const int l15 = lane & 15, g = lane >> 4;
  bf16x8 qf[8];
  const unsigned short* qp_ = Qp + ((size_t)b * 256 + qt) * 4096 + (size_t)lane * 8;
#pragma unroll
  for (int kk = 0; kk < 8; ++kk) qf[kk] = *(const bf16x8*)(qp_ + kk * 512);
  const unsigned short* Kb = Kp + (size_t)b * 1048576;
  const unsigned short* Vb = Vp + (size_t)b * 1048576;
  f32x4 acc[16];
  const f32x4 zero = {0.f, 0.f, 0.f, 0.f};
#pragma unroll
  for (int i = 0; i < 16; ++i) acc[i] = zero;
  float lacc[4] = {0.f, 0.f, 0.f, 0.f};

  // ---- fused dual chunk: chunks 2w (tiles tgA,tgA+1) and 2w+1 (+2,+3) ----
  const int t0A = s0 - WIN + 64 * w;
  const int tgA = qt - 8 + 4 * w;
  const int tg0 = min(max(tgA + 0, 0), 255);
  const int tg1 = min(max(tgA + 1, 0), 255);
  const int tg2 = min(max(tgA + 2, 0), 255);
  const int tg3 = min(max(tgA + 3, 0), 255);
  const unsigned short* k0p = Kb + (size_t)tg0 * 4096 + (size_t)lane * 8;
  const unsigned short* k1p = Kb + (size_t)tg1 * 4096 + (size_t)lane * 8;
  const unsigned short* k2p = Kb + (size_t)tg2 * 4096 + (size_t)lane * 8;
  const unsigned short* k3p = Kb + (size_t)tg3 * 4096 + (size_t)lane * 8;
  f32x4 sc0 = zero, sc1 = zero, sc2 = zero, sc3 = zero;
#pragma unroll
  for (int kk = 0; kk < 8; ++kk) {
    sc0 = MFMA16(qf[kk], *(const bf16x8*)(k0p + kk * 512), sc0);
    sc1 = MFMA16(qf[kk], *(const bf16x8*)(k1p + kk * 512), sc1);
    sc2 = MFMA16(qf[kk], *(const bf16x8*)(k2p + kk * 512), sc2);
    sc3 = MFMA16(qf[kk], *(const bf16x8*)(k3p + kk * 512), sc3);
  }
  float p[4][4];
#pragma unroll
  for (int r = 0; r < 4; ++r) {
    const int s = s0 + 4 * g + r;
    const f32x4 sv[4] = {sc0, sc1, sc2, sc3};
#pragma unroll
    for (int ti = 0; ti < 4; ++ti) {
      int t = t0A + 16 * ti + l15;
      bool ok = (t >= 0) && (t < SDIM) && (t - s <= WIN) && (t - s >= -WIN);
      p[ti][r] = ok ? __expf(sv[ti][r] * QSCALE) : 0.f;
    }
  }
#pragma unroll
  for (int r = 0; r < 4; ++r) {
    float v = p[0][r] + p[1][r] + p[2][r] + p[3][r];
    v += __shfl_xor(v, 1);
    v += __shfl_xor(v, 2);
    v += __shfl_xor(v, 4);
    v += __shfl_xor(v, 8);
    lacc[r] += v;
  }
#pragma unroll
  for (int r = 0; r < 4; ++r) {
    plds[w][0][4 * g + r][l15] = f2bf(p[0][r]);
    plds[w][0][4 * g + r][16 + l15] = f2bf(p[1][r]);
    plds[w][1][4 * g + r][l15] = f2bf(p[2][r]);
    plds[w][1][4 * g + r][16 + l15] = f2bf(p[3][r]);
  }
  bf16x8 paA = *(const bf16x8*)&plds[w][0][l15][8 * g];
  bf16x8 paB = *(const bf16x8*)&plds[w][1][l15][8 * g];
  const int tgvA = min(max(tgA + (g >> 1), 0), 255);
  const int tgvB = min(max(tgA + 2 + (g >> 1), 0), 255);
  const unsigned short* vpA =
      Vb + (size_t)tgvA * 4096 + (size_t)(g & 1) * 128 + (size_t)l15 * 8;
  const unsigned short* vpB =
      Vb + (size_t)tgvB * 4096 + (size_t)(g & 1) * 128 + (size_t)l15 * 8;
#pragma unroll
  for (int dt = 0; dt < 16; ++dt) {
    acc[dt] = MFMA16(paA, *(const bf16x8*)(vpA + dt * 256), acc[dt]);
    acc[dt] = MFMA16(paB, *(const bf16x8*)(vpB + dt * 256), acc[dt]);
  }

  // ---- wave 3 tail: half-chunk c8 (second 16-t tile fully masked) ----
  if (w == 3) {
    const int t0C = s0 + WIN;
    const int tgC = min(qt + 8, 255);
    const unsigned short* kcp = Kb + (size_t)tgC * 4096 + (size_t)lane * 8;
    f32x4 scC = zero;
#pragma unroll
    for (int kk = 0; kk < 8; ++kk)
      scC = MFMA16(qf[kk], *(const bf16x8*)(kcp + kk * 512), scC);
    float pC[4];
#pragma unroll
    for (int r = 0; r < 4; ++r) {
      int s = s0 + 4 * g + r;
      int t = t0C + l15;
      bool ok = (t < SDIM) && (t - s <= WIN);
      pC[r] = ok ? __expf(scC[r] * QSCALE) : 0.f;
      float v = pC[r];
      v += __shfl_xor(v, 1);
      v += __shfl_xor(v, 2);
      v += __shfl_xor(v, 4);
      v += __shfl_xor(v, 8);
      lacc[r] += v;
    }
#pragma unroll
    for (int r = 0; r < 4; ++r) {
      plds[w][0][4 * g + r][l15] = f2bf(pC[r]);
      plds[w][0][4 * g + r][16 + l15] = 0;
    }
    bf16x8 paC = *(const bf16x8*)&plds[w][0][l15][8 * g];
    const int tgvC = min(max(tgC + (g >> 1), 0), 255);
    const unsigned short* vpC =
        Vb + (size_t)tgvC * 4096 + (size_t)(g & 1) * 128 + (size_t)l15 * 8;
#pragma unroll
    for (int dt = 0; dt < 16; ++dt)
      acc[dt] = MFMA16(paC, *(const bf16x8*)(vpC + dt * 256), acc[dt]);
  }

  // ---- epilogue: combine, normalize, write partial ----
  if (l15 == 0) {
#pragma unroll
    for (int r = 0; r < 4; ++r) lsh[w][4 * g + r] = lacc[r];
  }
  __syncthreads();
  float li[4];
#pragma unroll
  for (int r = 0; r < 4; ++r)
    li[r] = 1.0f / (lsh[0][4 * g + r] + lsh[1][4 * g + r] + lsh[2][4 * g + r] +
                    lsh[3][4 * g + r]);
#pragma unroll
  for (int dt = 0; dt < 16; ++dt) {
    float s = acc[dt][0] * li[0] + acc[dt][1] * li[1] + acc[dt][2] * li[2] +
              acc[dt][3] * li[3];
    s += __shfl_xor(s, 16);
    s += __shfl_xor(s, 32);
    if (lane < 16) fbuf[w][dt * 16 + lane] = s;
  }
  __syncthreads();
  partial[(size_t)blk * HDIM + tid] =
      fbuf[0][tid] + fbuf[1][tid] + fbuf[2][tid] + fbuf[3][tid];

  // ---- ticket: last 64 arrivals perform the deterministic tail reduce ----
  __threadfence();  // partial row visible (device scope) before ticket
  if (tid == 0)
    ticket = __hip_atomic_fetch_add(cnt, 1u, __ATOMIC_ACQ_REL,
                                    __HIP_MEMORY_SCOPE_AGENT);
  __syncthreads();  // also orders all fbuf reads before reuse below
  const unsigned ret = ticket;
  if (ret >= 960u) {
    if (tid == 0) {
      while (__hip_atomic_load(cnt, __ATOMIC_ACQUIRE,
                               __HIP_MEMORY_SCOPE_AGENT) < 1024u)
        __builtin_amdgcn_s_sleep(2);
    }
    __syncthreads();
    __threadfence();  // all partials now visible
    const int idx = (int)(ret - 960u);
    const int b2 = idx >> 4, cx = idx & 15;  // task: batch b2, cols [16cx,16cx+16)
    float(*red)[17] = (float(*)[17]) & fbuf[0][0];  // 16x17 fits in fbuf
    const int lc = tid & 15, rg = tid >> 4;
    float s = 0.f;
#pragma unroll
    for (int i = 0; i < 16; ++i)
      s += partial[((size_t)b2 * 256 + rg * 16 + i) * HDIM + cx * 16 + lc];
    red[rg][lc] = s;
    __syncthreads();
    if (rg == 0) {
      float t = 0.f;
#pragma unroll
      for (int r = 0; r < 16; ++r) t += red[r][lc];
      out[(size_t)b2 * HDIM + cx * 16 + lc] = t * (1.0f / (float)SDIM);
    }
  }
}

extern "C" void kernel_launch(void* const* d_in, const int* in_sizes, int n_in,
                              void* d_out, int out_size, void* d_ws, size_t ws_size,
                              hipStream_t stream) {
  const float* x  = (const float*)d_in[0];
  const float* Wq = (const float*)d_in[1];
  const float* bq = (const float*)d_in[2];
  const float* Wk = (const float*)d_in[3];
  const float* bk = (const float*)d_in[4];
  const float* Wv = (const float*)d_in[5];
  const float* bv = (const float*)d_in[6];
  float* out = (float*)d_out;

  unsigned short* Wp = (unsigned short*)d_ws;           // 384 KB
  unsigned short* Qp = Wp + 3 * 65536;                  // 8.4 MB
  unsigned short* Kp = Qp + (size_t)NROW * HDIM;        // 8.4 MB
  unsigned short* Vp = Kp + (size_t)NROW * HDIM;        // 8.4 MB
  float* partial = (float*)(Vp + (size_t)NROW * HDIM);  // 1 MB
  unsigned* cnt = (unsigned*)(partial + (size_t)1024 * HDIM);

  hipMemsetAsync(cnt, 0, sizeof(unsigned), stream);
  dim3 wg(16, 3);
  wconv<<<wg, 256, 0, stream>>>(Wq, Wk, Wv, Wp);
  qkv_mfma<<<512, 256, 0, stream>>>(x, Wp, bq, bk, bv, Qp, Kp, Vp);
  attn_mfma<<<1024, 256, 0, stream>>>(Qp, Kp, Vp, partial, out, cnt);
}

// Round 19
// 48.794 us; speedup vs baseline: 3.1328x; 2.8441x over previous
//
#include <hip/hip_runtime.h>

#define SDIM 4096
#define HDIM 256
#define WIN 128
#define NROW 16384  // B*S
#define QSCALE 0.0625f  // 1/sqrt(256)

typedef __attribute__((ext_vector_type(8))) short bf16x8;
typedef __attribute__((ext_vector_type(4))) float f32x4;

static __device__ __forceinline__ unsigned short f2bf(float f) {
  unsigned int u = __float_as_uint(f);
  return (unsigned short)((u + 0x7fffu + ((u >> 16) & 1u)) >> 16);
}

#define MFMA16(a, b, c) __builtin_amdgcn_mfma_f32_16x16x32_bf16((a), (b), (c), 0, 0, 0)

// Frag-packed layout (per 16-row tile, per kk): pack[tile][kk][lane][j] =
//   M[16*tile + (lane&15)][32*kk + 8*(lane>>4) + j]  -> wave load = base+lane*8.
// V PV-packed: Vp[tile][dt][gg][l15][j] = V[16*tile + 8*gg + j][16*dt + l15].

// ---------- Kernel 0: W -> frag-packed bf16 W^T ----------
__global__ __launch_bounds__(256) void wconv(const float* __restrict__ Wq,
                                             const float* __restrict__ Wk,
                                             const float* __restrict__ Wv,
                                             unsigned short* __restrict__ Wp) {
  const int m = blockIdx.y, nt = blockIdx.x;
  const float* __restrict__ W = (m == 0) ? Wq : (m == 1) ? Wk : Wv;
  const int tid = threadIdx.x, lane = tid & 63, w = tid >> 6;
  const int l15 = lane & 15, g = lane >> 4;
#pragma unroll
  for (int half = 0; half < 2; ++half) {
    int kk = w * 2 + half;
    bf16x8 v;
#pragma unroll
    for (int j = 0; j < 8; ++j)
      v[j] = (short)f2bf(W[(size_t)(32 * kk + 8 * g + j) * HDIM + 16 * nt + l15]);
    *(bf16x8*)(Wp + ((size_t)(m * 16 + nt) * 8 + kk) * 512 + (size_t)lane * 8) = v;
  }
}

// ---------- Kernel 1: QKV (R13-proven: 512 blocks, 32 rows, 8 waves/CU) ----
__global__ __launch_bounds__(256) void qkv_mfma(
    const float* __restrict__ x, const unsigned short* __restrict__ Wp,
    const float* __restrict__ bq, const float* __restrict__ bk,
    const float* __restrict__ bv, unsigned short* __restrict__ Qp,
    unsigned short* __restrict__ Kp, unsigned short* __restrict__ Vp) {
  __shared__ unsigned short st[32][264];
  const int tid = threadIdx.x;
  const int lane = tid & 63, w = tid >> 6;
  const int l15 = lane & 15, g = lane >> 4;
  const size_t rb = (size_t)blockIdx.x * 32;
#pragma unroll
  for (int it = 0; it < 8; ++it) {
    int u = it * 256 + tid;
    int r = u >> 6, c4 = (u & 63) << 2;
    float4 f = *(const float4*)(x + (rb + r) * HDIM + c4);
    st[r][c4 + 0] = f2bf(f.x);
    st[r][c4 + 1] = f2bf(f.y);
    st[r][c4 + 2] = f2bf(f.z);
    st[r][c4 + 3] = f2bf(f.w);
  }
  __syncthreads();
  bf16x8 a[2][8];
#pragma unroll
  for (int rtl = 0; rtl < 2; ++rtl)
#pragma unroll
    for (int kk = 0; kk < 8; ++kk)
      a[rtl][kk] = *(const bf16x8*)&st[16 * rtl + l15][32 * kk + 8 * g];
  __syncthreads();
  const int tg0 = blockIdx.x * 2;
  for (int m = 0; m < 3; ++m) {
    const unsigned short* Wm = Wp + (size_t)m * 65536;
    const float* bias = (m == 0) ? bq : (m == 1) ? bk : bv;
#pragma unroll
    for (int ntl = 0; ntl < 4; ++ntl) {
      const int nt = 4 * w + ntl;
      const unsigned short* wp_ = Wm + (size_t)nt * 4096 + (size_t)lane * 8;
      bf16x8 wf[8];
#pragma unroll
      for (int kk = 0; kk < 8; ++kk) wf[kk] = *(const bf16x8*)(wp_ + kk * 512);
      f32x4 a0 = {0.f, 0.f, 0.f, 0.f}, a1 = {0.f, 0.f, 0.f, 0.f};
#pragma unroll
      for (int kk = 0; kk < 8; ++kk) {
        a0 = MFMA16(a[0][kk], wf[kk], a0);
        a1 = MFMA16(a[1][kk], wf[kk], a1);
      }
      float bn = bias[nt * 16 + l15];
#pragma unroll
      for (int r = 0; r < 4; ++r) {
        st[4 * g + r][nt * 16 + l15] = f2bf(a0[r] + bn);
        st[16 + 4 * g + r][nt * 16 + l15] = f2bf(a1[r] + bn);
      }
    }
    __syncthreads();
    if (m < 2) {
      unsigned short* O = (m == 0 ? Qp : Kp);
#pragma unroll
      for (int it = 0; it < 4; ++it) {
        int u = it * 256 + tid;
        int ln = u & 63, kk = (u >> 6) & 7, tgl = u >> 9;
        int lg = ln >> 4, lc = ln & 15;
        bf16x8 vv = *(const bf16x8*)&st[16 * tgl + lc][32 * kk + 8 * lg];
        *(bf16x8*)(O + ((size_t)(tg0 + tgl) * 8 + kk) * 512 + (size_t)ln * 8) = vv;
      }
    } else {
#pragma unroll
      for (int it = 0; it < 4; ++it) {
        int u = it * 256 + tid;
        int lc = u & 15, gg = (u >> 4) & 1, dt = (u >> 5) & 15, tgl = u >> 9;
        bf16x8 vv;
#pragma unroll
        for (int j = 0; j < 8; ++j)
          vv[j] = (short)st[16 * tgl + 8 * gg + j][16 * dt + lc];
        *(bf16x8*)(Vp + (size_t)(tg0 + tgl) * 4096 +
                   (size_t)(dt * 32 + gg * 16 + lc) * 8) = vv;
      }
    }
    __syncthreads();
  }
}

// ---------- Kernel 2: banded attention, fused dual-chunk per wave ----------
// grid 1024 (XCD-swizzled), block 256 = 4 waves. Wave w = chunks {2w, 2w+1}
// fully interleaved (one static body, max ILP); wave 3 appends half-chunk c8.
__global__ __launch_bounds__(256) void attn_mfma(
    const unsigned short* __restrict__ Qp, const unsigned short* __restrict__ Kp,
    const unsigned short* __restrict__ Vp, float* __restrict__ partial) {
  __shared__ unsigned short plds[4][2][16][40];  // 10.2 KB
  __shared__ float lsh[4][16];
  __shared__ float fbuf[4][256];  // 4 KB
  const int tid = threadIdx.x;
  const int lane = tid & 63, w = tid >> 6;
  const int bid = blockIdx.x;
  const int blk = (bid & 7) * 128 + (bid >> 3);  // bijective XCD swizzle
  const int b = blk >> 8;
  const int qt = blk & 255;
  const int s0 = qt << 4;
  const int l15 = lane & 15, g = lane >> 4;
  bf16x8 qf[8];
  const unsigned short* qp_ = Qp + ((size_t)b * 256 + qt) * 4096 + (size_t)lane * 8;
#pragma unroll
  for (int kk = 0; kk < 8; ++kk) qf[kk] = *(const bf16x8*)(qp_ + kk * 512);
  const unsigned short* Kb = Kp + (size_t)b * 1048576;
  const unsigned short* Vb = Vp + (size_t)b * 1048576;
  f32x4 acc[16];
  const f32x4 zero = {0.f, 0.f, 0.f, 0.f};
#pragma unroll
  for (int i = 0; i < 16; ++i) acc[i] = zero;
  float lacc[4] = {0.f, 0.f, 0.f, 0.f};

  // ---- fused dual chunk: chunks 2w (tiles tgA,tgA+1) and 2w+1 (+2,+3) ----
  const int t0A = s0 - WIN + 64 * w;  // multiple of 16
  const int tgA = qt - 8 + 4 * w;
  const int tg0 = min(max(tgA + 0, 0), 255);
  const int tg1 = min(max(tgA + 1, 0), 255);
  const int tg2 = min(max(tgA + 2, 0), 255);
  const int tg3 = min(max(tgA + 3, 0), 255);
  const unsigned short* k0p = Kb + (size_t)tg0 * 4096 + (size_t)lane * 8;
  const unsigned short* k1p = Kb + (size_t)tg1 * 4096 + (size_t)lane * 8;
  const unsigned short* k2p = Kb + (size_t)tg2 * 4096 + (size_t)lane * 8;
  const unsigned short* k3p = Kb + (size_t)tg3 * 4096 + (size_t)lane * 8;
  f32x4 sc0 = zero, sc1 = zero, sc2 = zero, sc3 = zero;
#pragma unroll
  for (int kk = 0; kk < 8; ++kk) {
    sc0 = MFMA16(qf[kk], *(const bf16x8*)(k0p + kk * 512), sc0);
    sc1 = MFMA16(qf[kk], *(const bf16x8*)(k1p + kk * 512), sc1);
    sc2 = MFMA16(qf[kk], *(const bf16x8*)(k2p + kk * 512), sc2);
    sc3 = MFMA16(qf[kk], *(const bf16x8*)(k3p + kk * 512), sc3);
  }
  float p[4][4];
#pragma unroll
  for (int r = 0; r < 4; ++r) {
    const int s = s0 + 4 * g + r;
    const f32x4 sv[4] = {sc0, sc1, sc2, sc3};
#pragma unroll
    for (int ti = 0; ti < 4; ++ti) {
      int t = t0A + 16 * ti + l15;
      bool ok = (t >= 0) && (t < SDIM) && (t - s <= WIN) && (t - s >= -WIN);
      p[ti][r] = ok ? __expf(sv[ti][r] * QSCALE) : 0.f;
    }
  }
#pragma unroll
  for (int r = 0; r < 4; ++r) {
    float v = p[0][r] + p[1][r] + p[2][r] + p[3][r];
    v += __shfl_xor(v, 1);
    v += __shfl_xor(v, 2);
    v += __shfl_xor(v, 4);
    v += __shfl_xor(v, 8);
    lacc[r] += v;
  }
#pragma unroll
  for (int r = 0; r < 4; ++r) {
    plds[w][0][4 * g + r][l15] = f2bf(p[0][r]);
    plds[w][0][4 * g + r][16 + l15] = f2bf(p[1][r]);
    plds[w][1][4 * g + r][l15] = f2bf(p[2][r]);
    plds[w][1][4 * g + r][16 + l15] = f2bf(p[3][r]);
  }
  bf16x8 paA = *(const bf16x8*)&plds[w][0][l15][8 * g];
  bf16x8 paB = *(const bf16x8*)&plds[w][1][l15][8 * g];
  const int tgvA = min(max(tgA + (g >> 1), 0), 255);
  const int tgvB = min(max(tgA + 2 + (g >> 1), 0), 255);
  const unsigned short* vpA =
      Vb + (size_t)tgvA * 4096 + (size_t)(g & 1) * 128 + (size_t)l15 * 8;
  const unsigned short* vpB =
      Vb + (size_t)tgvB * 4096 + (size_t)(g & 1) * 128 + (size_t)l15 * 8;
#pragma unroll
  for (int dt = 0; dt < 16; ++dt) {
    acc[dt] = MFMA16(paA, *(const bf16x8*)(vpA + dt * 256), acc[dt]);
    acc[dt] = MFMA16(paB, *(const bf16x8*)(vpB + dt * 256), acc[dt]);
  }

  // ---- wave 3 tail: half-chunk c8 (second 16-t tile fully masked) ----
  if (w == 3) {
    const int t0C = s0 + WIN;  // = s0 - 128 + 8*32
    const int tgC = min(qt + 8, 255);
    const unsigned short* kcp = Kb + (size_t)tgC * 4096 + (size_t)lane * 8;
    f32x4 scC = zero;
#pragma unroll
    for (int kk = 0; kk < 8; ++kk)
      scC = MFMA16(qf[kk], *(const bf16x8*)(kcp + kk * 512), scC);
    float pC[4];
#pragma unroll
    for (int r = 0; r < 4; ++r) {
      int s = s0 + 4 * g + r;
      int t = t0C + l15;
      bool ok = (t < SDIM) && (t - s <= WIN);  // t-s >= 113 > -WIN always
      pC[r] = ok ? __expf(scC[r] * QSCALE) : 0.f;
      float v = pC[r];
      v += __shfl_xor(v, 1);
      v += __shfl_xor(v, 2);
      v += __shfl_xor(v, 4);
      v += __shfl_xor(v, 8);
      lacc[r] += v;
    }
#pragma unroll
    for (int r = 0; r < 4; ++r) {
      plds[w][0][4 * g + r][l15] = f2bf(pC[r]);
      plds[w][0][4 * g + r][16 + l15] = 0;
    }
    bf16x8 paC = *(const bf16x8*)&plds[w][0][l15][8 * g];
    const int tgvC = min(max(tgC + (g >> 1), 0), 255);
    const unsigned short* vpC =
        Vb + (size_t)tgvC * 4096 + (size_t)(g & 1) * 128 + (size_t)l15 * 8;
#pragma unroll
    for (int dt = 0; dt < 16; ++dt)
      acc[dt] = MFMA16(paC, *(const bf16x8*)(vpC + dt * 256), acc[dt]);
  }

  // ---- epilogue: 2 barriers; li recomputed per-wave from lsh ----
  if (l15 == 0) {
#pragma unroll
    for (int r = 0; r < 4; ++r) lsh[w][4 * g + r] = lacc[r];
  }
  __syncthreads();
  float li[4];
#pragma unroll
  for (int r = 0; r < 4; ++r)
    li[r] = 1.0f / (lsh[0][4 * g + r] + lsh[1][4 * g + r] + lsh[2][4 * g + r] +
                    lsh[3][4 * g + r]);
#pragma unroll
  for (int dt = 0; dt < 16; ++dt) {
    float s = acc[dt][0] * li[0] + acc[dt][1] * li[1] + acc[dt][2] * li[2] +
              acc[dt][3] * li[3];
    s += __shfl_xor(s, 16);
    s += __shfl_xor(s, 32);
    if (lane < 16) fbuf[w][dt * 16 + lane] = s;
  }
  __syncthreads();
  partial[(size_t)blk * HDIM + tid] =
      fbuf[0][tid] + fbuf[1][tid] + fbuf[2][tid] + fbuf[3][tid];
}

// ---------- Kernel 3: deterministic mean over S ----------
__global__ __launch_bounds__(256) void reduce_partials(
    const float* __restrict__ partial, float* __restrict__ out) {
  __shared__ float red[16][17];
  const int cx = blockIdx.x, b = blockIdx.y;
  const int lc = threadIdx.x & 15, rg = threadIdx.x >> 4;
  float s = 0.f;
#pragma unroll
  for (int i = 0; i < 16; ++i)
    s += partial[((size_t)b * 256 + rg * 16 + i) * HDIM + cx * 16 + lc];
  red[rg][lc] = s;
  __syncthreads();
  if (rg == 0) {
    float t = 0.f;
#pragma unroll
    for (int r = 0; r < 16; ++r) t += red[r][lc];
    out[(size_t)b * HDIM + cx * 16 + lc] = t * (1.0f / (float)SDIM);
  }
}

extern "C" void kernel_launch(void* const* d_in, const int* in_sizes, int n_in,
                              void* d_out, int out_size, void* d_ws, size_t ws_size,
                              hipStream_t stream) {
  const float* x  = (const float*)d_in[0];
  const float* Wq = (const float*)d_in[1];
  const float* bq = (const float*)d_in[2];
  const float* Wk = (const float*)d_in[3];
  const float* bk = (const float*)d_in[4];
  const float* Wv = (const float*)d_in[5];
  const float* bv = (const float*)d_in[6];
  float* out = (float*)d_out;

  unsigned short* Wp = (unsigned short*)d_ws;           // 384 KB
  unsigned short* Qp = Wp + 3 * 65536;                  // 8.4 MB
  unsigned short* Kp = Qp + (size_t)NROW * HDIM;        // 8.4 MB
  unsigned short* Vp = Kp + (size_t)NROW * HDIM;        // 8.4 MB
  float* partial = (float*)(Vp + (size_t)NROW * HDIM);  // 1 MB

  dim3 wg(16, 3);
  wconv<<<wg, 256, 0, stream>>>(Wq, Wk, Wv, Wp);
  qkv_mfma<<<512, 256, 0, stream>>>(x, Wp, bq, bk, bv, Qp, Kp, Vp);
  attn_mfma<<<1024, 256, 0, stream>>>(Qp, Kp, Vp, partial);
  dim3 rg(16, 4);
  reduce_partials<<<rg, 256, 0, stream>>>(partial, out);
}

// Round 20
// 47.133 us; speedup vs baseline: 3.2432x; 1.0352x over previous
//
#include <hip/hip_runtime.h>

#define SDIM 4096
#define HDIM 256
#define WIN 128
#define NROW 16384  // B*S
#define QSCALE 0.0625f  // 1/sqrt(256)

typedef __attribute__((ext_vector_type(8))) short bf16x8;
typedef __attribute__((ext_vector_type(4))) float f32x4;

static __device__ __forceinline__ unsigned short f2bf(float f) {
  unsigned int u = __float_as_uint(f);
  return (unsigned short)((u + 0x7fffu + ((u >> 16) & 1u)) >> 16);
}

#define MFMA16(a, b, c) __builtin_amdgcn_mfma_f32_16x16x32_bf16((a), (b), (c), 0, 0, 0)

// Frag-packed layout (per 16-row tile, per kk): pack[tile][kk][lane][j] =
//   M[16*tile + (lane&15)][32*kk + 8*(lane>>4) + j]  -> wave load = base+lane*8.
// V PV-packed: Vp[tile][dt][gg][l15][j] = V[16*tile + 8*gg + j][16*dt + l15].

// ---------- Kernel 0: W -> frag-packed bf16 W^T (frozen) ----------
__global__ __launch_bounds__(256) void wconv(const float* __restrict__ Wq,
                                             const float* __restrict__ Wk,
                                             const float* __restrict__ Wv,
                                             unsigned short* __restrict__ Wp) {
  const int m = blockIdx.y, nt = blockIdx.x;
  const float* __restrict__ W = (m == 0) ? Wq : (m == 1) ? Wk : Wv;
  const int tid = threadIdx.x, lane = tid & 63, w = tid >> 6;
  const int l15 = lane & 15, g = lane >> 4;
#pragma unroll
  for (int half = 0; half < 2; ++half) {
    int kk = w * 2 + half;
    bf16x8 v;
#pragma unroll
    for (int j = 0; j < 8; ++j)
      v[j] = (short)f2bf(W[(size_t)(32 * kk + 8 * g + j) * HDIM + 16 * nt + l15]);
    *(bf16x8*)(Wp + ((size_t)(m * 16 + nt) * 8 + kk) * 512 + (size_t)lane * 8) = v;
  }
}

// ---------- Kernel 1: QKV (frozen R13 version) ----------
__global__ __launch_bounds__(256) void qkv_mfma(
    const float* __restrict__ x, const unsigned short* __restrict__ Wp,
    const float* __restrict__ bq, const float* __restrict__ bk,
    const float* __restrict__ bv, unsigned short* __restrict__ Qp,
    unsigned short* __restrict__ Kp, unsigned short* __restrict__ Vp) {
  __shared__ unsigned short st[32][264];
  const int tid = threadIdx.x;
  const int lane = tid & 63, w = tid >> 6;
  const int l15 = lane & 15, g = lane >> 4;
  const size_t rb = (size_t)blockIdx.x * 32;
#pragma unroll
  for (int it = 0; it < 8; ++it) {
    int u = it * 256 + tid;
    int r = u >> 6, c4 = (u & 63) << 2;
    float4 f = *(const float4*)(x + (rb + r) * HDIM + c4);
    st[r][c4 + 0] = f2bf(f.x);
    st[r][c4 + 1] = f2bf(f.y);
    st[r][c4 + 2] = f2bf(f.z);
    st[r][c4 + 3] = f2bf(f.w);
  }
  __syncthreads();
  bf16x8 a[2][8];
#pragma unroll
  for (int rtl = 0; rtl < 2; ++rtl)
#pragma unroll
    for (int kk = 0; kk < 8; ++kk)
      a[rtl][kk] = *(const bf16x8*)&st[16 * rtl + l15][32 * kk + 8 * g];
  __syncthreads();
  const int tg0 = blockIdx.x * 2;
  for (int m = 0; m < 3; ++m) {
    const unsigned short* Wm = Wp + (size_t)m * 65536;
    const float* bias = (m == 0) ? bq : (m == 1) ? bk : bv;
#pragma unroll
    for (int ntl = 0; ntl < 4; ++ntl) {
      const int nt = 4 * w + ntl;
      const unsigned short* wp_ = Wm + (size_t)nt * 4096 + (size_t)lane * 8;
      bf16x8 wf[8];
#pragma unroll
      for (int kk = 0; kk < 8; ++kk) wf[kk] = *(const bf16x8*)(wp_ + kk * 512);
      f32x4 a0 = {0.f, 0.f, 0.f, 0.f}, a1 = {0.f, 0.f, 0.f, 0.f};
#pragma unroll
      for (int kk = 0; kk < 8; ++kk) {
        a0 = MFMA16(a[0][kk], wf[kk], a0);
        a1 = MFMA16(a[1][kk], wf[kk], a1);
      }
      float bn = bias[nt * 16 + l15];
#pragma unroll
      for (int r = 0; r < 4; ++r) {
        st[4 * g + r][nt * 16 + l15] = f2bf(a0[r] + bn);
        st[16 + 4 * g + r][nt * 16 + l15] = f2bf(a1[r] + bn);
      }
    }
    __syncthreads();
    if (m < 2) {
      unsigned short* O = (m == 0 ? Qp : Kp);
#pragma unroll
      for (int it = 0; it < 4; ++it) {
        int u = it * 256 + tid;
        int ln = u & 63, kk = (u >> 6) & 7, tgl = u >> 9;
        int lg = ln >> 4, lc = ln & 15;
        bf16x8 vv = *(const bf16x8*)&st[16 * tgl + lc][32 * kk + 8 * lg];
        *(bf16x8*)(O + ((size_t)(tg0 + tgl) * 8 + kk) * 512 + (size_t)ln * 8) = vv;
      }
    } else {
#pragma unroll
      for (int it = 0; it < 4; ++it) {
        int u = it * 256 + tid;
        int lc = u & 15, gg = (u >> 4) & 1, dt = (u >> 5) & 15, tgl = u >> 9;
        bf16x8 vv;
#pragma unroll
        for (int j = 0; j < 8; ++j)
          vv[j] = (short)st[16 * tgl + 8 * gg + j][16 * dt + lc];
        *(bf16x8*)(Vp + (size_t)(tg0 + tgl) * 4096 +
                   (size_t)(dt * 32 + gg * 16 + lc) * 8) = vv;
      }
    }
    __syncthreads();
  }
}

// ---------- Kernel 2: banded attention, fused dual-chunk + V-A prefetch ----
// grid 1024 (XCD-swizzled), block 256 = 4 waves. Single lever vs R13: the
// first 8 V-A fragments are prefetched into registers right after the QK
// MFMAs issue, overlapping their L2 latency with the exp + LDS-P phase.
// launch_bounds(256,3): VGPR cap 170 (no spill), occupancy 12 waves/CU.
__global__ __launch_bounds__(256, 3) void attn_mfma(
    const unsigned short* __restrict__ Qp, const unsigned short* __restrict__ Kp,
    const unsigned short* __restrict__ Vp, float* __restrict__ partial) {
  __shared__ unsigned short plds[4][2][16][40];  // 10.2 KB
  __shared__ float lsh[4][16];
  __shared__ float fbuf[4][256];  // 4 KB
  const int tid = threadIdx.x;
  const int lane = tid & 63, w = tid >> 6;
  const int bid = blockIdx.x;
  const int blk = (bid & 7) * 128 + (bid >> 3);  // bijective XCD swizzle
  const int b = blk >> 8;
  const int qt = blk & 255;
  const int s0 = qt << 4;
  const int l15 = lane & 15, g = lane >> 4;
  bf16x8 qf[8];
  const unsigned short* qp_ = Qp + ((size_t)b * 256 + qt) * 4096 + (size_t)lane * 8;
#pragma unroll
  for (int kk = 0; kk < 8; ++kk) qf[kk] = *(const bf16x8*)(qp_ + kk * 512);
  const unsigned short* Kb = Kp + (size_t)b * 1048576;
  const unsigned short* Vb = Vp + (size_t)b * 1048576;
  f32x4 acc[16];
  const f32x4 zero = {0.f, 0.f, 0.f, 0.f};
#pragma unroll
  for (int i = 0; i < 16; ++i) acc[i] = zero;
  float lacc[4] = {0.f, 0.f, 0.f, 0.f};

  // ---- fused dual chunk: chunks 2w (tiles tgA,tgA+1) and 2w+1 (+2,+3) ----
  const int t0A = s0 - WIN + 64 * w;  // multiple of 16
  const int tgA = qt - 8 + 4 * w;
  const int tg0 = min(max(tgA + 0, 0), 255);
  const int tg1 = min(max(tgA + 1, 0), 255);
  const int tg2 = min(max(tgA + 2, 0), 255);
  const int tg3 = min(max(tgA + 3, 0), 255);
  const unsigned short* k0p = Kb + (size_t)tg0 * 4096 + (size_t)lane * 8;
  const unsigned short* k1p = Kb + (size_t)tg1 * 4096 + (size_t)lane * 8;
  const unsigned short* k2p = Kb + (size_t)tg2 * 4096 + (size_t)lane * 8;
  const unsigned short* k3p = Kb + (size_t)tg3 * 4096 + (size_t)lane * 8;
  f32x4 sc0 = zero, sc1 = zero, sc2 = zero, sc3 = zero;
#pragma unroll
  for (int kk = 0; kk < 8; ++kk) {
    sc0 = MFMA16(qf[kk], *(const bf16x8*)(k0p + kk * 512), sc0);
    sc1 = MFMA16(qf[kk], *(const bf16x8*)(k1p + kk * 512), sc1);
    sc2 = MFMA16(qf[kk], *(const bf16x8*)(k2p + kk * 512), sc2);
    sc3 = MFMA16(qf[kk], *(const bf16x8*)(k3p + kk * 512), sc3);
  }
  // ---- V-A prefetch: issue 8 frag loads now; latency hides under exp+LDS --
  const int tgvA = min(max(tgA + (g >> 1), 0), 255);
  const int tgvB = min(max(tgA + 2 + (g >> 1), 0), 255);
  const unsigned short* vpA =
      Vb + (size_t)tgvA * 4096 + (size_t)(g & 1) * 128 + (size_t)l15 * 8;
  const unsigned short* vpB =
      Vb + (size_t)tgvB * 4096 + (size_t)(g & 1) * 128 + (size_t)l15 * 8;
  bf16x8 vfA[8];
#pragma unroll
  for (int dt = 0; dt < 8; ++dt) vfA[dt] = *(const bf16x8*)(vpA + dt * 256);

  float p[4][4];
#pragma unroll
  for (int r = 0; r < 4; ++r) {
    const int s = s0 + 4 * g + r;
    const f32x4 sv[4] = {sc0, sc1, sc2, sc3};
#pragma unroll
    for (int ti = 0; ti < 4; ++ti) {
      int t = t0A + 16 * ti + l15;
      bool ok = (t >= 0) && (t < SDIM) && (t - s <= WIN) && (t - s >= -WIN);
      p[ti][r] = ok ? __expf(sv[ti][r] * QSCALE) : 0.f;
    }
  }
#pragma unroll
  for (int r = 0; r < 4; ++r) {
    float v = p[0][r] + p[1][r] + p[2][r] + p[3][r];
    v += __shfl_xor(v, 1);
    v += __shfl_xor(v, 2);
    v += __shfl_xor(v, 4);
    v += __shfl_xor(v, 8);
    lacc[r] += v;
  }
#pragma unroll
  for (int r = 0; r < 4; ++r) {
    plds[w][0][4 * g + r][l15] = f2bf(p[0][r]);
    plds[w][0][4 * g + r][16 + l15] = f2bf(p[1][r]);
    plds[w][1][4 * g + r][l15] = f2bf(p[2][r]);
    plds[w][1][4 * g + r][16 + l15] = f2bf(p[3][r]);
  }
  bf16x8 paA = *(const bf16x8*)&plds[w][0][l15][8 * g];
  bf16x8 paB = *(const bf16x8*)&plds[w][1][l15][8 * g];
  // ---- PV: A-pass (prefetched dt 0-7, inline dt 8-15), then B-pass ------
#pragma unroll
  for (int dt = 0; dt < 8; ++dt) acc[dt] = MFMA16(paA, vfA[dt], acc[dt]);
#pragma unroll
  for (int dt = 8; dt < 16; ++dt)
    acc[dt] = MFMA16(paA, *(const bf16x8*)(vpA + dt * 256), acc[dt]);
#pragma unroll
  for (int dt = 0; dt < 16; ++dt)
    acc[dt] = MFMA16(paB, *(const bf16x8*)(vpB + dt * 256), acc[dt]);

  // ---- wave 3 tail: half-chunk c8 (second 16-t tile fully masked) ----
  if (w == 3) {
    const int t0C = s0 + WIN;  // = s0 - 128 + 8*32
    const int tgC = min(qt + 8, 255);
    const unsigned short* kcp = Kb + (size_t)tgC * 4096 + (size_t)lane * 8;
    f32x4 scC = zero;
#pragma unroll
    for (int kk = 0; kk < 8; ++kk)
      scC = MFMA16(qf[kk], *(const bf16x8*)(kcp + kk * 512), scC);
    float pC[4];
#pragma unroll
    for (int r = 0; r < 4; ++r) {
      int s = s0 + 4 * g + r;
      int t = t0C + l15;
      bool ok = (t < SDIM) && (t - s <= WIN);  // t-s >= 113 > -WIN always
      pC[r] = ok ? __expf(scC[r] * QSCALE) : 0.f;
      float v = pC[r];
      v += __shfl_xor(v, 1);
      v += __shfl_xor(v, 2);
      v += __shfl_xor(v, 4);
      v += __shfl_xor(v, 8);
      lacc[r] += v;
    }
#pragma unroll
    for (int r = 0; r < 4; ++r) {
      plds[w][0][4 * g + r][l15] = f2bf(pC[r]);
      plds[w][0][4 * g + r][16 + l15] = 0;
    }
    bf16x8 paC = *(const bf16x8*)&plds[w][0][l15][8 * g];
    const int tgvC = min(max(tgC + (g >> 1), 0), 255);
    const unsigned short* vpC =
        Vb + (size_t)tgvC * 4096 + (size_t)(g & 1) * 128 + (size_t)l15 * 8;
#pragma unroll
    for (int dt = 0; dt < 16; ++dt)
      acc[dt] = MFMA16(paC, *(const bf16x8*)(vpC + dt * 256), acc[dt]);
  }

  // ---- epilogue: 2 barriers; li recomputed per-wave from lsh ----
  if (l15 == 0) {
#pragma unroll
    for (int r = 0; r < 4; ++r) lsh[w][4 * g + r] = lacc[r];
  }
  __syncthreads();
  float li[4];
#pragma unroll
  for (int r = 0; r < 4; ++r)
    li[r] = 1.0f / (lsh[0][4 * g + r] + lsh[1][4 * g + r] + lsh[2][4 * g + r] +
                    lsh[3][4 * g + r]);
#pragma unroll
  for (int dt = 0; dt < 16; ++dt) {
    float s = acc[dt][0] * li[0] + acc[dt][1] * li[1] + acc[dt][2] * li[2] +
              acc[dt][3] * li[3];
    s += __shfl_xor(s, 16);
    s += __shfl_xor(s, 32);
    if (lane < 16) fbuf[w][dt * 16 + lane] = s;
  }
  __syncthreads();
  partial[(size_t)blk * HDIM + tid] =
      fbuf[0][tid] + fbuf[1][tid] + fbuf[2][tid] + fbuf[3][tid];
}

// ---------- Kernel 3: deterministic mean over S (frozen) ----------
__global__ __launch_bounds__(256) void reduce_partials(
    const float* __restrict__ partial, float* __restrict__ out) {
  __shared__ float red[16][17];
  const int cx = blockIdx.x, b = blockIdx.y;
  const int lc = threadIdx.x & 15, rg = threadIdx.x >> 4;
  float s = 0.f;
#pragma unroll
  for (int i = 0; i < 16; ++i)
    s += partial[((size_t)b * 256 + rg * 16 + i) * HDIM + cx * 16 + lc];
  red[rg][lc] = s;
  __syncthreads();
  if (rg == 0) {
    float t = 0.f;
#pragma unroll
    for (int r = 0; r < 16; ++r) t += red[r][lc];
    out[(size_t)b * HDIM + cx * 16 + lc] = t * (1.0f / (float)SDIM);
  }
}

extern "C" void kernel_launch(void* const* d_in, const int* in_sizes, int n_in,
                              void* d_out, int out_size, void* d_ws, size_t ws_size,
                              hipStream_t stream) {
  const float* x  = (const float*)d_in[0];
  const float* Wq = (const float*)d_in[1];
  const float* bq = (const float*)d_in[2];
  const float* Wk = (const float*)d_in[3];
  const float* bk = (const float*)d_in[4];
  const float* Wv = (const float*)d_in[5];
  const float* bv = (const float*)d_in[6];
  float* out = (float*)d_out;

  unsigned short* Wp = (unsigned short*)d_ws;           // 384 KB
  unsigned short* Qp = Wp + 3 * 65536;                  // 8.4 MB
  unsigned short* Kp = Qp + (size_t)NROW * HDIM;        // 8.4 MB
  unsigned short* Vp = Kp + (size_t)NROW * HDIM;        // 8.4 MB
  float* partial = (float*)(Vp + (size_t)NROW * HDIM);  // 1 MB

  dim3 wg(16, 3);
  wconv<<<wg, 256, 0, stream>>>(Wq, Wk, Wv, Wp);
  qkv_mfma<<<512, 256, 0, stream>>>(x, Wp, bq, bk, bv, Qp, Kp, Vp);
  attn_mfma<<<1024, 256, 0, stream>>>(Qp, Kp, Vp, partial);
  dim3 rg(16, 4);
  reduce_partials<<<rg, 256, 0, stream>>>(partial, out);
}